// Round 6
// baseline (232.927 us; speedup 1.0000x reference)
//
#include <hip/hip_runtime.h>

#define B_ 2
#define L_ 2048
#define C_ 2048
#define H_ 16
#define HKV_ 4
#define D_ 128
#define G_ (H_ / HKV_)
#define TOK_ (B_ * L_)
#define NQKV_ 3072  // H*D + 2*HKV*D

typedef __bf16 bf16;
typedef __bf16 bf16x4 __attribute__((ext_vector_type(4)));
typedef __bf16 bf16x8 __attribute__((ext_vector_type(8)));
typedef float f32x4 __attribute__((ext_vector_type(4)));

__device__ inline void gload16(const void* g, void* l) {
  __builtin_amdgcn_global_load_lds(
      (const __attribute__((address_space(1))) void*)g,
      (__attribute__((address_space(3))) void*)l, 16, 0, 0);
}

// ---------------- fp32 -> bf16 conversion ----------------
__global__ void cvt_bf16(const float* __restrict__ in, bf16* __restrict__ out, int n4) {
  int stride = gridDim.x * blockDim.x;
  for (int j = blockIdx.x * blockDim.x + threadIdx.x; j < n4; j += stride) {
    float4 v = reinterpret_cast<const float4*>(in)[j];
    bf16x4 o = {(bf16)v.x, (bf16)v.y, (bf16)v.z, (bf16)v.w};
    reinterpret_cast<bf16x4*>(out)[j] = o;
  }
}

// ---------------- GEMM: C[M,N] = A[M,K] @ B[N,K]^T (bf16 in, f32 acc) ------
// 256x128 tile, BK=64, 8 waves (4Mx2N, 64x64 each), 3-slot LDS ring with
// counted vmcnt(6) at tile boundaries (T3+T4): prefetch t+2 stays in flight
// across the barrier; slot distance 2 => provably race-free.
template <bool OUT_F32>
__global__ __launch_bounds__(512) void gemm_bt(
    const bf16* __restrict__ A, const bf16* __restrict__ Bm,
    void* __restrict__ Cm, int M, int N, int K) {
  __shared__ __align__(16) bf16 sA[3][256 * 64];
  __shared__ __align__(16) bf16 sB[3][128 * 64];
  const int tid = threadIdx.x;
  const int wid = tid >> 6, lane = tid & 63;
  const int row0 = blockIdx.x * 256, col0 = blockIdx.y * 128;
  const int wwr = wid & 3, wwc = wid >> 2;
  const int l15 = lane & 15, g4 = lane >> 4;
  // staging coords: thread -> (row = tid>>3, 16B-chunk = tid&7), pre-swizzled src
  const int ra = tid >> 3, ca = tid & 7;
  const bf16* gA = A + (size_t)(row0 + ra) * K + ((ca ^ (ra & 7)) << 3);
  const bf16* gB = Bm + (size_t)(col0 + ra) * K + ((ca ^ (ra & 7)) << 3);
  const int ldsOff = tid * 8;  // linear dest (wave-uniform base + lane*16B)
  const int nk = K >> 6;

  auto stage = [&](int kt, int slot) {
    const bf16* a = gA + kt * 64;
    const bf16* b = gB + kt * 64;
#pragma unroll
    for (int j = 0; j < 4; ++j)
      gload16(a + (size_t)(64 * j) * K, &sA[slot][ldsOff + j * 64 * 64]);
#pragma unroll
    for (int j = 0; j < 2; ++j)
      gload16(b + (size_t)(64 * j) * K, &sB[slot][ldsOff + j * 64 * 64]);
  };

  f32x4 acc[4][4] = {};
  stage(0, 0);
  stage(1, 1);
  asm volatile("s_waitcnt vmcnt(6)" ::: "memory");  // tile 0 landed
  __builtin_amdgcn_s_barrier();
  __builtin_amdgcn_sched_barrier(0);

  int slot = 0;
  for (int kt = 0; kt < nk; ++kt) {
    int s2 = slot + 2; if (s2 >= 3) s2 -= 3;
    if (kt + 2 < nk) stage(kt + 2, s2);
    const bf16* cA = sA[slot];
    const bf16* cB = sB[slot];
#pragma unroll
    for (int kh = 0; kh < 2; ++kh) {
      bf16x8 af[4], bfr[4];
      const int ch = (((kh << 2) + g4) ^ (l15 & 7)) << 3;
#pragma unroll
      for (int m = 0; m < 4; ++m)
        af[m] = *reinterpret_cast<const bf16x8*>(cA + (wwr * 64 + m * 16 + l15) * 64 + ch);
#pragma unroll
      for (int n = 0; n < 4; ++n)
        bfr[n] = *reinterpret_cast<const bf16x8*>(cB + (wwc * 64 + n * 16 + l15) * 64 + ch);
      __builtin_amdgcn_s_setprio(1);
#pragma unroll
      for (int m = 0; m < 4; ++m)
#pragma unroll
        for (int n = 0; n < 4; ++n)
          acc[m][n] = __builtin_amdgcn_mfma_f32_16x16x32_bf16(af[m], bfr[n], acc[m][n], 0, 0, 0);
      __builtin_amdgcn_s_setprio(0);
    }
    if (kt + 2 < nk)
      asm volatile("s_waitcnt vmcnt(6)" ::: "memory");  // t+1 landed, t+2 in flight
    else
      asm volatile("s_waitcnt vmcnt(0)" ::: "memory");
    __builtin_amdgcn_s_barrier();
    __builtin_amdgcn_sched_barrier(0);
    slot = (slot + 1 == 3) ? 0 : slot + 1;
  }
  // epilogue
#pragma unroll
  for (int m = 0; m < 4; ++m)
#pragma unroll
    for (int n = 0; n < 4; ++n)
#pragma unroll
      for (int r = 0; r < 4; ++r) {
        int row = row0 + wwr * 64 + m * 16 + g4 * 4 + r;
        int col = col0 + wwc * 64 + n * 16 + l15;
        if constexpr (OUT_F32)
          reinterpret_cast<float*>(Cm)[(size_t)row * N + col] = acc[m][n][r];
        else
          reinterpret_cast<bf16*>(Cm)[(size_t)row * N + col] = (bf16)acc[m][n][r];
      }
}

// ---------------- RMSNorm + RoPE for K, relayout to (B, HKV, L, D) ---------
__global__ void k_norm_rope(const bf16* __restrict__ proj,  // (TOK, NQKV)
                            const float* __restrict__ normw,
                            const float* __restrict__ cosb,  // (L, 64)
                            const float* __restrict__ sinb,
                            bf16* __restrict__ out) {  // (B, HKV, L, D)
  int wid = (blockIdx.x * blockDim.x + threadIdx.x) >> 6;
  int lane = threadIdx.x & 63;
  int head = wid & 3, tok = wid >> 2;
  int b = tok / L_, l = tok % L_;
  const bf16* p = proj + (size_t)tok * NQKV_ + H_ * D_ + head * D_;
  float t1 = (float)p[lane];
  float t2 = (float)p[lane + 64];
  float ss = t1 * t1 + t2 * t2;
#pragma unroll
  for (int off = 32; off; off >>= 1) ss += __shfl_xor(ss, off);
  float r = rsqrtf(ss * (1.0f / 128.0f) + 1e-6f);
  float n1 = t1 * r * normw[lane];
  float n2 = t2 * r * normw[lane + 64];
  float c = cosb[l * 64 + lane], s = sinb[l * 64 + lane];
  bf16* q = out + (((size_t)b * HKV_ + head) * L_ + l) * D_;
  q[lane] = (bf16)(n1 * c - n2 * s);
  q[lane + 64] = (bf16)(n2 * c + n1 * s);
}

// ---------------- V transpose (LDS-tiled): (TOK,NQKV col 2560+) -> (B,HKV,D,L)
__global__ __launch_bounds__(256) void v_transpose(const bf16* __restrict__ proj,
                                                   bf16* __restrict__ vt) {
  __shared__ __align__(16) bf16 sT[64 * 136];
  const int t = threadIdx.x;
  const int l0 = blockIdx.x * 64;
  const int bk = blockIdx.y;  // b*HKV+h
  const bf16* src = proj + (size_t)((bk >> 2) * L_ + l0) * NQKV_ + (H_ + HKV_) * D_ + (bk & 3) * D_;
#pragma unroll
  for (int c = 0; c < 4; ++c) {
    int idx = c * 256 + t;
    int l = idx >> 4, dc = idx & 15;
    bf16x8 v = *reinterpret_cast<const bf16x8*>(src + (size_t)l * NQKV_ + dc * 8);
    *reinterpret_cast<bf16x8*>((char*)sT + l * 272 + ((dc ^ (l >> 3)) << 4)) = v;
  }
  __syncthreads();
  bf16* dst = vt + (size_t)bk * D_ * L_ + l0;
#pragma unroll
  for (int c = 0; c < 4; ++c) {
    int idx = c * 256 + t;
    int d = idx >> 3, lg = idx & 7;
    bf16x8 o;
#pragma unroll
    for (int j = 0; j < 8; ++j) {
      int l = lg * 8 + j;
      o[j] = *reinterpret_cast<const bf16*>((char*)sT + l * 272 + (((d >> 3) ^ lg) << 4) + (d & 7) * 2);
    }
    *reinterpret_cast<bf16x8*>(dst + (size_t)d * L_ + lg * 8) = o;
  }
}

// ---------------- Fused flash attention, block-causal, GQA -----------------
// 512 thr = 8 waves = 4 heads x 2 q-subtiles(16 rows) over 32 q rows.
// Swapped QK^T (S^T = K*Q^T): each lane owns one q-row -> scalar softmax
// state, 4x b64 P-writes, packed epilogue. Double-buffered K/V staging.
__global__ __launch_bounds__(512, 4) void attn_fused(
    const bf16* __restrict__ QKV,  // (TOK, NQKV) raw projections
    const bf16* __restrict__ Kn,   // (B,HKV,L,D) normed+roped
    const bf16* __restrict__ Vt,   // (B,HKV,D,L)
    const float* __restrict__ qnw,
    const float* __restrict__ cosb, const float* __restrict__ sinb,
    bf16* __restrict__ AO) {  // (B,L,H,D)
  __shared__ __align__(16) bf16 sK[2][64 * 128];
  __shared__ __align__(16) bf16 sV[2][64 * 128];
  __shared__ __align__(16) bf16 sP[8 * 16 * 64];
  const int tid = threadIdx.x;
  const int wid = tid >> 6, lane = tid & 63;
  const int bid = blockIdx.x;
  const int bk = bid & 7;  // same-bk blocks land on same XCD (bid%8)
  // balanced pairing: co-resident bid and bid+256 have complementary work
  const int qt = (bid < 256) ? (bid >> 3) : 63 - ((bid - 256) >> 3);
  const int b = bk >> 2;
  const int hl = wid & 3, qs = wid >> 2;
  const int h = (bk & 3) * G_ + hl;
  const int qrow0 = qt * 32 + qs * 16;
  const int l15 = lane & 15, g4 = lane >> 4, kk = g4 * 8;
  const int swz = (l15 & 7) << 4;

  // ---- fused Q: load + RMSNorm + RoPE (row = qrow0 + l15) ----
  const int qrow = qrow0 + l15;
  const bf16* qsrc = QKV + (size_t)(b * L_ + qrow) * NQKV_ + h * D_;
  float t[4][8];
  float ss = 0.f;
#pragma unroll
  for (int c = 0; c < 4; ++c) {
    bf16x8 v = *reinterpret_cast<const bf16x8*>(qsrc + c * 32 + kk);
#pragma unroll
    for (int j = 0; j < 8; ++j) { t[c][j] = (float)v[j]; ss += t[c][j] * t[c][j]; }
  }

  // staging coordinates (pre-swizzled global sources, linear LDS dest)
  const int kr0 = tid >> 4, kc0 = tid & 15;
  const int kr1 = 32 + kr0;
  const int vr0 = tid >> 3, vc0 = tid & 7;
  const int vr1 = 64 + vr0;
  const bf16* kb = Kn + (size_t)bk * L_ * D_;
  const bf16* vb = Vt + (size_t)bk * D_ * (size_t)L_;
  const bf16* kp0 = kb + (size_t)kr0 * D_ + ((kc0 ^ (kr0 & 7)) * 8);
  const bf16* kp1 = kb + (size_t)kr1 * D_ + ((kc0 ^ (kr1 & 7)) * 8);
  const bf16* vp0 = vb + (size_t)vr0 * L_ + ((vc0 ^ (vr0 & 7)) * 8);
  const bf16* vp1 = vb + (size_t)vr1 * L_ + ((vc0 ^ (vr1 & 7)) * 8);

  const int ntiles = ((qt >> 3) + 1) * 4;  // multiple of 4 -> kt-unroll-2 safe
  // prologue stage tile 0 -> buf 0 (flies while we do Q norm math)
  gload16(kp0, &sK[0][tid * 8]);
  gload16(kp1, &sK[0][(512 + tid) * 8]);
  gload16(vp0, &sV[0][tid * 8]);
  gload16(vp1, &sV[0][(512 + tid) * 8]);

  // Q norm math (overlaps staging); fold scale*log2e into Q fragments
  constexpr float SCL = 0.12752650038632816f;  // 128^-0.5 * log2(e)
  ss += __shfl_xor(ss, 16);
  ss += __shfl_xor(ss, 32);
  const float rr = rsqrtf(ss * (1.0f / 128.0f) + 1e-6f);
  bf16x8 qf[4];
#pragma unroll
  for (int c = 0; c < 2; ++c)
#pragma unroll
    for (int j = 0; j < 8; ++j) {
      int i = c * 32 + kk + j;
      float n1 = t[c][j] * rr * qnw[i];
      float n2 = t[c + 2][j] * rr * qnw[i + 64];
      float cs = cosb[qrow * 64 + i], sn = sinb[qrow * 64 + i];
      qf[c][j] = (bf16)((n1 * cs - n2 * sn) * SCL);
      qf[c + 2][j] = (bf16)((n2 * cs + n1 * sn) * SCL);
    }

  char* myP = (char*)(sP + wid * 16 * 64);
  f32x4 acc[8] = {};
  float mref = -1e30f, lpart = 0.f;

  __syncthreads();  // tile 0 staged (compiler drains vmcnt before barrier)

  // one kv-tile step; buffer choice is compile-time via manual unroll-2
  auto tile_step = [&](const bf16* sKc, const bf16* sVc, bf16* sKn_, bf16* sVn_,
                       int ktNext, bool doPref) {
    if (doPref) {
      gload16(kp0 + (size_t)ktNext * 64 * D_, &sKn_[tid * 8]);
      gload16(kp1 + (size_t)ktNext * 64 * D_, &sKn_[(512 + tid) * 8]);
      gload16(vp0 + ktNext * 64, &sVn_[tid * 8]);
      gload16(vp1 + ktNext * 64, &sVn_[(512 + tid) * 8]);
    }
    const char* cK = (const char*)sKc;
    const char* cV = (const char*)sVc;
    // --- swapped QK^T: s[n][r] = Sscaled[qrow=l15][key=16n+4g4+r] ---
    f32x4 s[4];
    __builtin_amdgcn_s_setprio(1);
#pragma unroll
    for (int n = 0; n < 4; ++n) {
      f32x4 st = {};
#pragma unroll
      for (int c = 0; c < 4; ++c) {
        int byte = (n * 16 + l15) * 256 + ((((c << 2) + g4) ^ (l15 & 7)) << 4);
        bf16x8 kf = *reinterpret_cast<const bf16x8*>(cK + byte);
        st = __builtin_amdgcn_mfma_f32_16x16x32_bf16(kf, qf[c], st, 0, 0, 0);
      }
      s[n] = st;
    }
    __builtin_amdgcn_s_setprio(0);
    // --- defer-max online softmax (scalar per lane: one q-row) ---
    float pm = fmaxf(fmaxf(s[0][0], s[0][1]), fmaxf(s[0][2], s[0][3]));
#pragma unroll
    for (int n = 1; n < 4; ++n)
      pm = fmaxf(pm, fmaxf(fmaxf(s[n][0], s[n][1]), fmaxf(s[n][2], s[n][3])));
    if (!__all(pm <= mref + 8.f)) {  // rare: true max grew -> reduce, rescale
      pm = fmaxf(pm, __shfl_xor(pm, 16));
      pm = fmaxf(pm, __shfl_xor(pm, 32));
      float mnew = fmaxf(mref, pm);
      float resc = exp2f(mref - mnew);
      mref = mnew;
      lpart *= resc;
#pragma unroll
      for (int f = 0; f < 8; ++f) acc[f] *= resc;
    }
#pragma unroll
    for (int n = 0; n < 4; ++n)
#pragma unroll
      for (int r = 0; r < 4; ++r) {
        float p = exp2f(s[n][r] - mref);
        s[n][r] = p;
        lpart += p;
      }
    // --- P -> LDS: 4 x ds_write_b64 (4 consecutive keys per reg group) ---
#pragma unroll
    for (int n = 0; n < 4; ++n) {
      bf16x4 pw = {(bf16)s[n][0], (bf16)s[n][1], (bf16)s[n][2], (bf16)s[n][3]};
      *reinterpret_cast<bf16x4*>(myP + l15 * 128 + (((n << 5) + (g4 << 3)) ^ swz)) = pw;
    }
    bf16x8 pf0 = *reinterpret_cast<const bf16x8*>(myP + l15 * 128 + ((g4 << 4) ^ swz));
    bf16x8 pf1 = *reinterpret_cast<const bf16x8*>(myP + l15 * 128 + ((64 + (g4 << 4)) ^ swz));
    // --- PV: O^T = mfma(V^T, P^T) ---
    __builtin_amdgcn_s_setprio(1);
#pragma unroll
    for (int f = 0; f < 8; ++f) {
      int d = f * 16 + l15;
      bf16x8 vf0 = *reinterpret_cast<const bf16x8*>(cV + d * 128 + ((g4 ^ (l15 & 7)) << 4));
      acc[f] = __builtin_amdgcn_mfma_f32_16x16x32_bf16(vf0, pf0, acc[f], 0, 0, 0);
      bf16x8 vf1 = *reinterpret_cast<const bf16x8*>(cV + d * 128 + (((4 + g4) ^ (l15 & 7)) << 4));
      acc[f] = __builtin_amdgcn_mfma_f32_16x16x32_bf16(vf1, pf1, acc[f], 0, 0, 0);
    }
    __builtin_amdgcn_s_setprio(0);
    __syncthreads();  // drains this iter's prefetch (late) + releases buffers
  };

  for (int kt = 0; kt < ntiles; kt += 2) {
    tile_step(sK[0], sV[0], sK[1], sV[1], kt + 1, true);
    tile_step(sK[1], sV[1], sK[0], sV[0], kt + 2, kt + 2 < ntiles);
  }

  // --- epilogue: reduce row-sum over the 4 lane-groups, packed stores ---
  lpart += __shfl_xor(lpart, 16);
  lpart += __shfl_xor(lpart, 32);
  const float rinv = 1.f / lpart;
  bf16* aop = AO + ((size_t)(b * L_ + qrow0 + l15) * H_ + h) * D_ + (g4 << 2);
#pragma unroll
  for (int f = 0; f < 8; ++f) {
    bf16x4 o = {(bf16)(acc[f][0] * rinv), (bf16)(acc[f][1] * rinv),
                (bf16)(acc[f][2] * rinv), (bf16)(acc[f][3] * rinv)};
    *reinterpret_cast<bf16x4*>(aop + f * 16) = o;
  }
}

// ---------------- launch ----------------
extern "C" void kernel_launch(void* const* d_in, const int* in_sizes, int n_in,
                              void* d_out, int out_size, void* d_ws, size_t ws_size,
                              hipStream_t stream) {
  const float* x = (const float*)d_in[0];
  const float* Wq = (const float*)d_in[1];
  const float* Wk = (const float*)d_in[2];
  const float* Wv = (const float*)d_in[3];
  const float* Wo = (const float*)d_in[4];
  const float* qnw = (const float*)d_in[5];
  const float* knw = (const float*)d_in[6];
  const float* rc = (const float*)d_in[7];
  const float* rs = (const float*)d_in[8];
  float* out = (float*)d_out;

  char* ws = (char*)d_ws;
  bf16* xb = (bf16*)ws;    ws += (size_t)TOK_ * C_ * 2;
  bf16* wqb = (bf16*)ws;   ws += (size_t)(H_ * D_) * C_ * 2;   // wq/wk/wv contiguous!
  bf16* wkb = (bf16*)ws;   ws += (size_t)(HKV_ * D_) * C_ * 2;
  bf16* wvb = (bf16*)ws;   ws += (size_t)(HKV_ * D_) * C_ * 2;
  bf16* wob = (bf16*)ws;   ws += (size_t)C_ * (H_ * D_) * 2;
  bf16* qkv = (bf16*)ws;   ws += (size_t)TOK_ * NQKV_ * 2;
  bf16* Kb = (bf16*)ws;    ws += (size_t)TOK_ * HKV_ * D_ * 2;
  bf16* Vtb = (bf16*)ws;   ws += (size_t)TOK_ * HKV_ * D_ * 2;
  bf16* AOb = xb;  // alias: xb dead after projection GEMM

  auto cvt = [&](const float* src, bf16* dst, size_t n) {
    int n4 = (int)(n / 4);
    int grid = (n4 + 255) / 256;
    if (grid > 4096) grid = 4096;
    cvt_bf16<<<grid, 256, 0, stream>>>(src, dst, n4);
  };
  cvt(x, xb, (size_t)TOK_ * C_);
  cvt(Wq, wqb, (size_t)H_ * D_ * C_);
  cvt(Wk, wkb, (size_t)HKV_ * D_ * C_);
  cvt(Wv, wvb, (size_t)HKV_ * D_ * C_);
  cvt(Wo, wob, (size_t)C_ * H_ * D_);

  // fused QKV projection: N = 3072 (wq,wk,wv rows contiguous)
  gemm_bt<false><<<dim3(TOK_ / 256, NQKV_ / 128), 512, 0, stream>>>(
      xb, wqb, qkv, TOK_, NQKV_, C_);

  k_norm_rope<<<(TOK_ * HKV_) / 4, 256, 0, stream>>>(qkv, knw, rc, rs, Kb);
  v_transpose<<<dim3(L_ / 64, B_ * HKV_), 256, 0, stream>>>(qkv, Vtb);

  attn_fused<<<512, 512, 0, stream>>>(qkv, Kb, Vtb, qnw, rc, rs, AOb);

  gemm_bt<true><<<dim3(TOK_ / 256, C_ / 128), 512, 0, stream>>>(
      AOb, wob, out, TOK_, C_, H_ * D_);
}

// Round 7
// 207.540 us; speedup vs baseline: 1.1223x; 1.1223x over previous
//
#include <hip/hip_runtime.h>

#define B_ 2
#define L_ 2048
#define C_ 2048
#define H_ 16
#define HKV_ 4
#define D_ 128
#define G_ (H_ / HKV_)
#define TOK_ (B_ * L_)
#define NQKV_ 3072  // H*D + 2*HKV*D

typedef __bf16 bf16;
typedef __bf16 bf16x4 __attribute__((ext_vector_type(4)));
typedef __bf16 bf16x8 __attribute__((ext_vector_type(8)));
typedef float f32x4 __attribute__((ext_vector_type(4)));

__device__ inline void gload16(const void* g, void* l) {
  __builtin_amdgcn_global_load_lds(
      (const __attribute__((address_space(1))) void*)g,
      (__attribute__((address_space(3))) void*)l, 16, 0, 0);
}

// ---------------- fp32 -> bf16 conversion ----------------
__global__ void cvt_bf16(const float* __restrict__ in, bf16* __restrict__ out, int n4) {
  int stride = gridDim.x * blockDim.x;
  for (int j = blockIdx.x * blockDim.x + threadIdx.x; j < n4; j += stride) {
    float4 v = reinterpret_cast<const float4*>(in)[j];
    bf16x4 o = {(bf16)v.x, (bf16)v.y, (bf16)v.z, (bf16)v.w};
    reinterpret_cast<bf16x4*>(out)[j] = o;
  }
}

// ---------------- GEMM: C[M,N] = A[M,K] @ B[N,K]^T (bf16 in, f32 acc) ------
// 128x128 tile, BK=32, 4 waves (2x2, 64x64 each). 3-slot LDS ring (48 KB ->
// 3 blocks/CU for stall hiding) with counted vmcnt(4): prefetch t+2 stays in
// flight across the barrier; slot distance 2 => race-free.
template <bool OUT_F32>
__global__ __launch_bounds__(256, 3) void gemm_bt(
    const bf16* __restrict__ A, const bf16* __restrict__ Bm,
    void* __restrict__ Cm, int M, int N, int K) {
  __shared__ __align__(16) bf16 sA[3][128 * 32];
  __shared__ __align__(16) bf16 sB[3][128 * 32];
  const int tid = threadIdx.x;
  const int row0 = blockIdx.x * 128, col0 = blockIdx.y * 128;
  const int wid = tid >> 6, lane = tid & 63;
  const int wr = wid >> 1, wc = wid & 1;
  const int l15 = lane & 15, kk = (lane >> 4) * 8;
  f32x4 acc[4][4] = {};
  const int nk = K / 32;
  const int r0 = tid >> 2, c0 = tid & 3;      // chunk f0 = tid
  const int r1 = 64 + r0, c1 = c0;            // chunk f1 = 256 + tid
  const int ldsA0 = (wid * 64) * 8, ldsA1 = (256 + wid * 64) * 8;

  auto stage = [&](int kt, int slot) {
    gload16(A + (size_t)(row0 + r0) * K + kt * 32 + c0 * 8, &sA[slot][ldsA0]);
    gload16(A + (size_t)(row0 + r1) * K + kt * 32 + c1 * 8, &sA[slot][ldsA1]);
    gload16(Bm + (size_t)(col0 + r0) * K + kt * 32 + c0 * 8, &sB[slot][ldsA0]);
    gload16(Bm + (size_t)(col0 + r1) * K + kt * 32 + c1 * 8, &sB[slot][ldsA1]);
  };

  stage(0, 0);
  stage(1, 1);
  asm volatile("s_waitcnt vmcnt(4)" ::: "memory");  // tile 0 landed
  __builtin_amdgcn_s_barrier();
  __builtin_amdgcn_sched_barrier(0);

  int slot = 0;
  for (int kt = 0; kt < nk; ++kt) {
    int s2 = slot + 2; if (s2 >= 3) s2 -= 3;
    if (kt + 2 < nk) stage(kt + 2, s2);
    const bf16* cA = sA[slot];
    const bf16* cB = sB[slot];
    bf16x8 af[4], bfr[4];
#pragma unroll
    for (int m = 0; m < 4; ++m)
      af[m] = *reinterpret_cast<const bf16x8*>(cA + (wr * 64 + m * 16 + l15) * 32 + kk);
#pragma unroll
    for (int n = 0; n < 4; ++n)
      bfr[n] = *reinterpret_cast<const bf16x8*>(cB + (wc * 64 + n * 16 + l15) * 32 + kk);
    __builtin_amdgcn_s_setprio(1);
#pragma unroll
    for (int m = 0; m < 4; ++m)
#pragma unroll
      for (int n = 0; n < 4; ++n)
        acc[m][n] = __builtin_amdgcn_mfma_f32_16x16x32_bf16(af[m], bfr[n], acc[m][n], 0, 0, 0);
    __builtin_amdgcn_s_setprio(0);
    if (kt + 2 < nk)
      asm volatile("s_waitcnt vmcnt(4)" ::: "memory");  // t+1 landed, t+2 in flight
    else
      asm volatile("s_waitcnt vmcnt(0)" ::: "memory");
    __builtin_amdgcn_s_barrier();
    __builtin_amdgcn_sched_barrier(0);
    slot = (slot + 1 == 3) ? 0 : slot + 1;
  }
  // epilogue
#pragma unroll
  for (int m = 0; m < 4; ++m)
#pragma unroll
    for (int n = 0; n < 4; ++n)
#pragma unroll
      for (int r = 0; r < 4; ++r) {
        int row = row0 + wr * 64 + m * 16 + (lane >> 4) * 4 + r;
        int col = col0 + wc * 64 + n * 16 + l15;
        if constexpr (OUT_F32)
          reinterpret_cast<float*>(Cm)[(size_t)row * N + col] = acc[m][n][r];
        else
          reinterpret_cast<bf16*>(Cm)[(size_t)row * N + col] = (bf16)acc[m][n][r];
      }
}

// ---------------- RMSNorm + RoPE for K, relayout to (B, HKV, L, D) ---------
__global__ void k_norm_rope(const bf16* __restrict__ proj,  // (TOK, NQKV)
                            const float* __restrict__ normw,
                            const float* __restrict__ cosb,  // (L, 64)
                            const float* __restrict__ sinb,
                            bf16* __restrict__ out) {  // (B, HKV, L, D)
  int wid = (blockIdx.x * blockDim.x + threadIdx.x) >> 6;
  int lane = threadIdx.x & 63;
  int head = wid & 3, tok = wid >> 2;
  int b = tok / L_, l = tok % L_;
  const bf16* p = proj + (size_t)tok * NQKV_ + H_ * D_ + head * D_;
  float t1 = (float)p[lane];
  float t2 = (float)p[lane + 64];
  float ss = t1 * t1 + t2 * t2;
#pragma unroll
  for (int off = 32; off; off >>= 1) ss += __shfl_xor(ss, off);
  float r = rsqrtf(ss * (1.0f / 128.0f) + 1e-6f);
  float n1 = t1 * r * normw[lane];
  float n2 = t2 * r * normw[lane + 64];
  float c = cosb[l * 64 + lane], s = sinb[l * 64 + lane];
  bf16* q = out + (((size_t)b * HKV_ + head) * L_ + l) * D_;
  q[lane] = (bf16)(n1 * c - n2 * s);
  q[lane + 64] = (bf16)(n2 * c + n1 * s);
}

// ---------------- V transpose (LDS-tiled): (TOK,NQKV col 2560+) -> (B,HKV,D,L)
__global__ __launch_bounds__(256) void v_transpose(const bf16* __restrict__ proj,
                                                   bf16* __restrict__ vt) {
  __shared__ __align__(16) bf16 sT[64 * 136];
  const int t = threadIdx.x;
  const int l0 = blockIdx.x * 64;
  const int bk = blockIdx.y;  // b*HKV+h
  const bf16* src = proj + (size_t)((bk >> 2) * L_ + l0) * NQKV_ + (H_ + HKV_) * D_ + (bk & 3) * D_;
#pragma unroll
  for (int c = 0; c < 4; ++c) {
    int idx = c * 256 + t;
    int l = idx >> 4, dc = idx & 15;
    bf16x8 v = *reinterpret_cast<const bf16x8*>(src + (size_t)l * NQKV_ + dc * 8);
    *reinterpret_cast<bf16x8*>((char*)sT + l * 272 + ((dc ^ (l >> 3)) << 4)) = v;
  }
  __syncthreads();
  bf16* dst = vt + (size_t)bk * D_ * L_ + l0;
#pragma unroll
  for (int c = 0; c < 4; ++c) {
    int idx = c * 256 + t;
    int d = idx >> 3, lg = idx & 7;
    bf16x8 o;
#pragma unroll
    for (int j = 0; j < 8; ++j) {
      int l = lg * 8 + j;
      o[j] = *reinterpret_cast<const bf16*>((char*)sT + l * 272 + (((d >> 3) ^ lg) << 4) + (d & 7) * 2);
    }
    *reinterpret_cast<bf16x8*>(dst + (size_t)d * L_ + lg * 8) = o;
  }
}

// ---------------- Fused flash attention, block-causal, GQA -----------------
// 512 thr = 8 waves = 4 heads x 2 q-subtiles(16 rows) over 32 q rows.
// Swapped QK^T (S^T = K*Q^T): each lane owns one q-row -> scalar softmax
// state, 4x b64 P-writes, packed epilogue. Double-buffered K/V staging.
__global__ __launch_bounds__(512, 4) void attn_fused(
    const bf16* __restrict__ QKV,  // (TOK, NQKV) raw projections
    const bf16* __restrict__ Kn,   // (B,HKV,L,D) normed+roped
    const bf16* __restrict__ Vt,   // (B,HKV,D,L)
    const float* __restrict__ qnw,
    const float* __restrict__ cosb, const float* __restrict__ sinb,
    bf16* __restrict__ AO) {  // (B,L,H,D)
  __shared__ __align__(16) bf16 sK[2][64 * 128];
  __shared__ __align__(16) bf16 sV[2][64 * 128];
  __shared__ __align__(16) bf16 sP[8 * 16 * 64];
  const int tid = threadIdx.x;
  const int wid = tid >> 6, lane = tid & 63;
  const int bid = blockIdx.x;
  const int bk = bid & 7;  // same-bk blocks land on same XCD (bid%8)
  // balanced pairing: co-resident bid and bid+256 have complementary work
  const int qt = (bid < 256) ? (bid >> 3) : 63 - ((bid - 256) >> 3);
  const int b = bk >> 2;
  const int hl = wid & 3, qs = wid >> 2;
  const int h = (bk & 3) * G_ + hl;
  const int qrow0 = qt * 32 + qs * 16;
  const int l15 = lane & 15, g4 = lane >> 4, kk = g4 * 8;
  const int swz = (l15 & 7) << 4;

  // ---- fused Q: load + RMSNorm + RoPE (row = qrow0 + l15) ----
  const int qrow = qrow0 + l15;
  const bf16* qsrc = QKV + (size_t)(b * L_ + qrow) * NQKV_ + h * D_;
  float t[4][8];
  float ss = 0.f;
#pragma unroll
  for (int c = 0; c < 4; ++c) {
    bf16x8 v = *reinterpret_cast<const bf16x8*>(qsrc + c * 32 + kk);
#pragma unroll
    for (int j = 0; j < 8; ++j) { t[c][j] = (float)v[j]; ss += t[c][j] * t[c][j]; }
  }

  // staging coordinates (pre-swizzled global sources, linear LDS dest)
  const int kr0 = tid >> 4, kc0 = tid & 15;
  const int kr1 = 32 + kr0;
  const int vr0 = tid >> 3, vc0 = tid & 7;
  const int vr1 = 64 + vr0;
  const bf16* kb = Kn + (size_t)bk * L_ * D_;
  const bf16* vb = Vt + (size_t)bk * D_ * (size_t)L_;
  const bf16* kp0 = kb + (size_t)kr0 * D_ + ((kc0 ^ (kr0 & 7)) * 8);
  const bf16* kp1 = kb + (size_t)kr1 * D_ + ((kc0 ^ (kr1 & 7)) * 8);
  const bf16* vp0 = vb + (size_t)vr0 * L_ + ((vc0 ^ (vr0 & 7)) * 8);
  const bf16* vp1 = vb + (size_t)vr1 * L_ + ((vc0 ^ (vr1 & 7)) * 8);

  const int ntiles = ((qt >> 3) + 1) * 4;  // multiple of 4 -> kt-unroll-2 safe
  // prologue stage tile 0 -> buf 0 (flies while we do Q norm math)
  gload16(kp0, &sK[0][tid * 8]);
  gload16(kp1, &sK[0][(512 + tid) * 8]);
  gload16(vp0, &sV[0][tid * 8]);
  gload16(vp1, &sV[0][(512 + tid) * 8]);

  // Q norm math (overlaps staging); fold scale*log2e into Q fragments
  constexpr float SCL = 0.12752650038632816f;  // 128^-0.5 * log2(e)
  ss += __shfl_xor(ss, 16);
  ss += __shfl_xor(ss, 32);
  const float rr = rsqrtf(ss * (1.0f / 128.0f) + 1e-6f);
  bf16x8 qf[4];
#pragma unroll
  for (int c = 0; c < 2; ++c)
#pragma unroll
    for (int j = 0; j < 8; ++j) {
      int i = c * 32 + kk + j;
      float n1 = t[c][j] * rr * qnw[i];
      float n2 = t[c + 2][j] * rr * qnw[i + 64];
      float cs = cosb[qrow * 64 + i], sn = sinb[qrow * 64 + i];
      qf[c][j] = (bf16)((n1 * cs - n2 * sn) * SCL);
      qf[c + 2][j] = (bf16)((n2 * cs + n1 * sn) * SCL);
    }

  char* myP = (char*)(sP + wid * 16 * 64);
  f32x4 acc[8] = {};
  float mref = -1e30f, lpart = 0.f;

  __syncthreads();  // tile 0 staged (compiler drains vmcnt before barrier)

  // one kv-tile step; buffer choice is compile-time via manual unroll-2
  auto tile_step = [&](const bf16* sKc, const bf16* sVc, bf16* sKn_, bf16* sVn_,
                       int ktNext, bool doPref) {
    if (doPref) {
      gload16(kp0 + (size_t)ktNext * 64 * D_, &sKn_[tid * 8]);
      gload16(kp1 + (size_t)ktNext * 64 * D_, &sKn_[(512 + tid) * 8]);
      gload16(vp0 + ktNext * 64, &sVn_[tid * 8]);
      gload16(vp1 + ktNext * 64, &sVn_[(512 + tid) * 8]);
    }
    const char* cK = (const char*)sKc;
    const char* cV = (const char*)sVc;
    // --- swapped QK^T: s[n][r] = Sscaled[qrow=l15][key=16n+4g4+r] ---
    f32x4 s[4];
    __builtin_amdgcn_s_setprio(1);
#pragma unroll
    for (int n = 0; n < 4; ++n) {
      f32x4 st = {};
#pragma unroll
      for (int c = 0; c < 4; ++c) {
        int byte = (n * 16 + l15) * 256 + ((((c << 2) + g4) ^ (l15 & 7)) << 4);
        bf16x8 kf = *reinterpret_cast<const bf16x8*>(cK + byte);
        st = __builtin_amdgcn_mfma_f32_16x16x32_bf16(kf, qf[c], st, 0, 0, 0);
      }
      s[n] = st;
    }
    __builtin_amdgcn_s_setprio(0);
    // --- defer-max online softmax (scalar per lane: one q-row) ---
    float pm = fmaxf(fmaxf(s[0][0], s[0][1]), fmaxf(s[0][2], s[0][3]));
#pragma unroll
    for (int n = 1; n < 4; ++n)
      pm = fmaxf(pm, fmaxf(fmaxf(s[n][0], s[n][1]), fmaxf(s[n][2], s[n][3])));
    if (!__all(pm <= mref + 8.f)) {  // rare: true max grew -> reduce, rescale
      pm = fmaxf(pm, __shfl_xor(pm, 16));
      pm = fmaxf(pm, __shfl_xor(pm, 32));
      float mnew = fmaxf(mref, pm);
      float resc = exp2f(mref - mnew);
      mref = mnew;
      lpart *= resc;
#pragma unroll
      for (int f = 0; f < 8; ++f) acc[f] *= resc;
    }
#pragma unroll
    for (int n = 0; n < 4; ++n)
#pragma unroll
      for (int r = 0; r < 4; ++r) {
        float p = exp2f(s[n][r] - mref);
        s[n][r] = p;
        lpart += p;
      }
    // --- P -> LDS: 4 x ds_write_b64 (4 consecutive keys per reg group) ---
#pragma unroll
    for (int n = 0; n < 4; ++n) {
      bf16x4 pw = {(bf16)s[n][0], (bf16)s[n][1], (bf16)s[n][2], (bf16)s[n][3]};
      *reinterpret_cast<bf16x4*>(myP + l15 * 128 + (((n << 5) + (g4 << 3)) ^ swz)) = pw;
    }
    bf16x8 pf0 = *reinterpret_cast<const bf16x8*>(myP + l15 * 128 + ((g4 << 4) ^ swz));
    bf16x8 pf1 = *reinterpret_cast<const bf16x8*>(myP + l15 * 128 + ((64 + (g4 << 4)) ^ swz));
    // --- PV: O^T = mfma(V^T, P^T) ---
    __builtin_amdgcn_s_setprio(1);
#pragma unroll
    for (int f = 0; f < 8; ++f) {
      int d = f * 16 + l15;
      bf16x8 vf0 = *reinterpret_cast<const bf16x8*>(cV + d * 128 + ((g4 ^ (l15 & 7)) << 4));
      acc[f] = __builtin_amdgcn_mfma_f32_16x16x32_bf16(vf0, pf0, acc[f], 0, 0, 0);
      bf16x8 vf1 = *reinterpret_cast<const bf16x8*>(cV + d * 128 + (((4 + g4) ^ (l15 & 7)) << 4));
      acc[f] = __builtin_amdgcn_mfma_f32_16x16x32_bf16(vf1, pf1, acc[f], 0, 0, 0);
    }
    __builtin_amdgcn_s_setprio(0);
    __syncthreads();  // drains this iter's prefetch (late) + releases buffers
  };

  for (int kt = 0; kt < ntiles; kt += 2) {
    tile_step(sK[0], sV[0], sK[1], sV[1], kt + 1, true);
    tile_step(sK[1], sV[1], sK[0], sV[0], kt + 2, kt + 2 < ntiles);
  }

  // --- epilogue: reduce row-sum over the 4 lane-groups, packed stores ---
  lpart += __shfl_xor(lpart, 16);
  lpart += __shfl_xor(lpart, 32);
  const float rinv = 1.f / lpart;
  bf16* aop = AO + ((size_t)(b * L_ + qrow0 + l15) * H_ + h) * D_ + (g4 << 2);
#pragma unroll
  for (int f = 0; f < 8; ++f) {
    bf16x4 o = {(bf16)(acc[f][0] * rinv), (bf16)(acc[f][1] * rinv),
                (bf16)(acc[f][2] * rinv), (bf16)(acc[f][3] * rinv)};
    *reinterpret_cast<bf16x4*>(aop + f * 16) = o;
  }
}

// ---------------- launch ----------------
extern "C" void kernel_launch(void* const* d_in, const int* in_sizes, int n_in,
                              void* d_out, int out_size, void* d_ws, size_t ws_size,
                              hipStream_t stream) {
  const float* x = (const float*)d_in[0];
  const float* Wq = (const float*)d_in[1];
  const float* Wk = (const float*)d_in[2];
  const float* Wv = (const float*)d_in[3];
  const float* Wo = (const float*)d_in[4];
  const float* qnw = (const float*)d_in[5];
  const float* knw = (const float*)d_in[6];
  const float* rc = (const float*)d_in[7];
  const float* rs = (const float*)d_in[8];
  float* out = (float*)d_out;

  char* ws = (char*)d_ws;
  bf16* xb = (bf16*)ws;    ws += (size_t)TOK_ * C_ * 2;
  bf16* wqb = (bf16*)ws;   ws += (size_t)(H_ * D_) * C_ * 2;   // wq/wk/wv contiguous!
  bf16* wkb = (bf16*)ws;   ws += (size_t)(HKV_ * D_) * C_ * 2;
  bf16* wvb = (bf16*)ws;   ws += (size_t)(HKV_ * D_) * C_ * 2;
  bf16* wob = (bf16*)ws;   ws += (size_t)C_ * (H_ * D_) * 2;
  bf16* qkv = (bf16*)ws;   ws += (size_t)TOK_ * NQKV_ * 2;
  bf16* Kb = (bf16*)ws;    ws += (size_t)TOK_ * HKV_ * D_ * 2;
  bf16* Vtb = (bf16*)ws;   ws += (size_t)TOK_ * HKV_ * D_ * 2;
  bf16* AOb = xb;  // alias: xb dead after projection GEMM

  auto cvt = [&](const float* src, bf16* dst, size_t n) {
    int n4 = (int)(n / 4);
    int grid = (n4 + 255) / 256;
    if (grid > 4096) grid = 4096;
    cvt_bf16<<<grid, 256, 0, stream>>>(src, dst, n4);
  };
  cvt(x, xb, (size_t)TOK_ * C_);
  cvt(Wq, wqb, (size_t)H_ * D_ * C_);
  cvt(Wk, wkb, (size_t)HKV_ * D_ * C_);
  cvt(Wv, wvb, (size_t)HKV_ * D_ * C_);
  cvt(Wo, wob, (size_t)C_ * H_ * D_);

  // fused QKV projection: N = 3072 (wq,wk,wv rows contiguous)
  gemm_bt<false><<<dim3(TOK_ / 128, NQKV_ / 128), 256, 0, stream>>>(
      xb, wqb, qkv, TOK_, NQKV_, C_);

  k_norm_rope<<<(TOK_ * HKV_) / 4, 256, 0, stream>>>(qkv, knw, rc, rs, Kb);
  v_transpose<<<dim3(L_ / 64, B_ * HKV_), 256, 0, stream>>>(qkv, Vtb);

  attn_fused<<<512, 512, 0, stream>>>(qkv, Kb, Vtb, qnw, rc, rs, AOb);

  gemm_bt<true><<<dim3(TOK_ / 128, C_ / 128), 256, 0, stream>>>(
      AOb, wob, out, TOK_, C_, H_ * D_);
}

// Round 8
// 201.004 us; speedup vs baseline: 1.1588x; 1.0325x over previous
//
#include <hip/hip_runtime.h>

#define B_ 2
#define L_ 2048
#define C_ 2048
#define H_ 16
#define HKV_ 4
#define D_ 128
#define G_ (H_ / HKV_)
#define TOK_ (B_ * L_)
#define NQKV_ 3072  // H*D + 2*HKV*D

typedef __bf16 bf16;
typedef __bf16 bf16x4 __attribute__((ext_vector_type(4)));
typedef __bf16 bf16x8 __attribute__((ext_vector_type(8)));
typedef float f32x4 __attribute__((ext_vector_type(4)));

__device__ inline void gload16(const void* g, void* l) {
  __builtin_amdgcn_global_load_lds(
      (const __attribute__((address_space(1))) void*)g,
      (__attribute__((address_space(3))) void*)l, 16, 0, 0);
}

// ---------------- fused fp32 -> bf16 conversion (x, Wq, Wk, Wv, Wo) --------
// dst segments are contiguous in workspace: xb|wqb|wkb|wvb|wob.
#define N4_X  2097152
#define N4_WQ 1048576
#define N4_WK 262144
#define N4_WV 262144
#define N4_WO 1048576
#define N4_TOT (N4_X + N4_WQ + N4_WK + N4_WV + N4_WO)

__global__ void cvt_all(const float* __restrict__ x, const float* __restrict__ wq,
                        const float* __restrict__ wk, const float* __restrict__ wv,
                        const float* __restrict__ wo, bf16* __restrict__ dst) {
  int stride = gridDim.x * blockDim.x;
  for (int j = blockIdx.x * blockDim.x + threadIdx.x; j < N4_TOT; j += stride) {
    const float* s;
    int off;
    if (j < N4_X) { s = x; off = j; }
    else if (j < N4_X + N4_WQ) { s = wq; off = j - N4_X; }
    else if (j < N4_X + N4_WQ + N4_WK) { s = wk; off = j - (N4_X + N4_WQ); }
    else if (j < N4_X + N4_WQ + N4_WK + N4_WV) { s = wv; off = j - (N4_X + N4_WQ + N4_WK); }
    else { s = wo; off = j - (N4_X + N4_WQ + N4_WK + N4_WV); }
    float4 v = reinterpret_cast<const float4*>(s)[off];
    bf16x4 o = {(bf16)v.x, (bf16)v.y, (bf16)v.z, (bf16)v.w};
    reinterpret_cast<bf16x4*>(dst)[j] = o;
  }
}

// ---------------- GEMM: C[M,N] = A[M,K] @ B[N,K]^T (bf16 in, f32 acc) ------
// 128x128 tile, BK=32, 4 waves (2x2, 64x64 each). 3-slot LDS ring (48 KB ->
// 3 blocks/CU for stall hiding) with counted vmcnt(4): prefetch t+2 stays in
// flight across the barrier; slot distance 2 => race-free.
template <bool OUT_F32>
__global__ __launch_bounds__(256, 3) void gemm_bt(
    const bf16* __restrict__ A, const bf16* __restrict__ Bm,
    void* __restrict__ Cm, int M, int N, int K) {
  __shared__ __align__(16) bf16 sA[3][128 * 32];
  __shared__ __align__(16) bf16 sB[3][128 * 32];
  const int tid = threadIdx.x;
  const int row0 = blockIdx.x * 128, col0 = blockIdx.y * 128;
  const int wid = tid >> 6, lane = tid & 63;
  const int wr = wid >> 1, wc = wid & 1;
  const int l15 = lane & 15, kk = (lane >> 4) * 8;
  f32x4 acc[4][4] = {};
  const int nk = K / 32;
  const int r0 = tid >> 2, c0 = tid & 3;      // chunk f0 = tid
  const int r1 = 64 + r0, c1 = c0;            // chunk f1 = 256 + tid
  const int ldsA0 = (wid * 64) * 8, ldsA1 = (256 + wid * 64) * 8;

  auto stage = [&](int kt, int slot) {
    gload16(A + (size_t)(row0 + r0) * K + kt * 32 + c0 * 8, &sA[slot][ldsA0]);
    gload16(A + (size_t)(row0 + r1) * K + kt * 32 + c1 * 8, &sA[slot][ldsA1]);
    gload16(Bm + (size_t)(col0 + r0) * K + kt * 32 + c0 * 8, &sB[slot][ldsA0]);
    gload16(Bm + (size_t)(col0 + r1) * K + kt * 32 + c1 * 8, &sB[slot][ldsA1]);
  };

  stage(0, 0);
  stage(1, 1);
  asm volatile("s_waitcnt vmcnt(4)" ::: "memory");  // tile 0 landed
  __builtin_amdgcn_s_barrier();
  __builtin_amdgcn_sched_barrier(0);

  int slot = 0;
  for (int kt = 0; kt < nk; ++kt) {
    int s2 = slot + 2; if (s2 >= 3) s2 -= 3;
    if (kt + 2 < nk) stage(kt + 2, s2);
    const bf16* cA = sA[slot];
    const bf16* cB = sB[slot];
    bf16x8 af[4], bfr[4];
#pragma unroll
    for (int m = 0; m < 4; ++m)
      af[m] = *reinterpret_cast<const bf16x8*>(cA + (wr * 64 + m * 16 + l15) * 32 + kk);
#pragma unroll
    for (int n = 0; n < 4; ++n)
      bfr[n] = *reinterpret_cast<const bf16x8*>(cB + (wc * 64 + n * 16 + l15) * 32 + kk);
    __builtin_amdgcn_s_setprio(1);
#pragma unroll
    for (int m = 0; m < 4; ++m)
#pragma unroll
      for (int n = 0; n < 4; ++n)
        acc[m][n] = __builtin_amdgcn_mfma_f32_16x16x32_bf16(af[m], bfr[n], acc[m][n], 0, 0, 0);
    __builtin_amdgcn_s_setprio(0);
    if (kt + 2 < nk)
      asm volatile("s_waitcnt vmcnt(4)" ::: "memory");  // t+1 landed, t+2 in flight
    else
      asm volatile("s_waitcnt vmcnt(0)" ::: "memory");
    __builtin_amdgcn_s_barrier();
    __builtin_amdgcn_sched_barrier(0);
    slot = (slot + 1 == 3) ? 0 : slot + 1;
  }
  // epilogue
#pragma unroll
  for (int m = 0; m < 4; ++m)
#pragma unroll
    for (int n = 0; n < 4; ++n)
#pragma unroll
      for (int r = 0; r < 4; ++r) {
        int row = row0 + wr * 64 + m * 16 + (lane >> 4) * 4 + r;
        int col = col0 + wc * 64 + n * 16 + l15;
        if constexpr (OUT_F32)
          reinterpret_cast<float*>(Cm)[(size_t)row * N + col] = acc[m][n][r];
        else
          reinterpret_cast<bf16*>(Cm)[(size_t)row * N + col] = (bf16)acc[m][n][r];
      }
}

// ---------------- RMSNorm + RoPE for K, relayout to (B, HKV, L, D) ---------
__global__ void k_norm_rope(const bf16* __restrict__ proj,  // (TOK, NQKV)
                            const float* __restrict__ normw,
                            const float* __restrict__ cosb,  // (L, 64)
                            const float* __restrict__ sinb,
                            bf16* __restrict__ out) {  // (B, HKV, L, D)
  int wid = (blockIdx.x * blockDim.x + threadIdx.x) >> 6;
  int lane = threadIdx.x & 63;
  int head = wid & 3, tok = wid >> 2;
  int b = tok / L_, l = tok % L_;
  const bf16* p = proj + (size_t)tok * NQKV_ + H_ * D_ + head * D_;
  float t1 = (float)p[lane];
  float t2 = (float)p[lane + 64];
  float ss = t1 * t1 + t2 * t2;
#pragma unroll
  for (int off = 32; off; off >>= 1) ss += __shfl_xor(ss, off);
  float r = rsqrtf(ss * (1.0f / 128.0f) + 1e-6f);
  float n1 = t1 * r * normw[lane];
  float n2 = t2 * r * normw[lane + 64];
  float c = cosb[l * 64 + lane], s = sinb[l * 64 + lane];
  bf16* q = out + (((size_t)b * HKV_ + head) * L_ + l) * D_;
  q[lane] = (bf16)(n1 * c - n2 * s);
  q[lane + 64] = (bf16)(n2 * c + n1 * s);
}

// ---------------- V transpose (LDS-tiled): (TOK,NQKV col 2560+) -> (B,HKV,D,L)
__global__ __launch_bounds__(256) void v_transpose(const bf16* __restrict__ proj,
                                                   bf16* __restrict__ vt) {
  __shared__ __align__(16) bf16 sT[64 * 136];
  const int t = threadIdx.x;
  const int l0 = blockIdx.x * 64;
  const int bk = blockIdx.y;  // b*HKV+h
  const bf16* src = proj + (size_t)((bk >> 2) * L_ + l0) * NQKV_ + (H_ + HKV_) * D_ + (bk & 3) * D_;
#pragma unroll
  for (int c = 0; c < 4; ++c) {
    int idx = c * 256 + t;
    int l = idx >> 4, dc = idx & 15;
    bf16x8 v = *reinterpret_cast<const bf16x8*>(src + (size_t)l * NQKV_ + dc * 8);
    *reinterpret_cast<bf16x8*>((char*)sT + l * 272 + ((dc ^ (l >> 3)) << 4)) = v;
  }
  __syncthreads();
  bf16* dst = vt + (size_t)bk * D_ * L_ + l0;
#pragma unroll
  for (int c = 0; c < 4; ++c) {
    int idx = c * 256 + t;
    int d = idx >> 3, lg = idx & 7;
    bf16x8 o;
#pragma unroll
    for (int j = 0; j < 8; ++j) {
      int l = lg * 8 + j;
      o[j] = *reinterpret_cast<const bf16*>((char*)sT + l * 272 + (((d >> 3) ^ lg) << 4) + (d & 7) * 2);
    }
    *reinterpret_cast<bf16x8*>(dst + (size_t)d * L_ + lg * 8) = o;
  }
}

// ---------------- Fused flash attention, block-causal, GQA -----------------
// 512 thr = 8 waves = 4 heads x 2 q-subtiles(16 rows) over 32 q rows.
// Swapped QK^T, scalar defer-max softmax, double-buffered K/V staging.
// This round: single smem block + precomputed loop-invariant LDS addresses;
// all per-tile LDS ops are base-VGPR + compile-time immediate.
// smem layout: K0@0 K1@16K V0@32K V1@48K P@64K(+wid*2K)  (K/V imms < 64K)
#define SM_K0 0
#define SM_K1 16384
#define SM_V0 32768
#define SM_V1 49152
#define SM_P  65536
__global__ __launch_bounds__(512, 4) void attn_fused(
    const bf16* __restrict__ QKV,  // (TOK, NQKV) raw projections
    const bf16* __restrict__ Kn,   // (B,HKV,L,D) normed+roped
    const bf16* __restrict__ Vt,   // (B,HKV,D,L)
    const float* __restrict__ qnw,
    const float* __restrict__ cosb, const float* __restrict__ sinb,
    bf16* __restrict__ AO) {  // (B,L,H,D)
  __shared__ __align__(16) char smem[81920];
  const int tid = threadIdx.x;
  const int wid = tid >> 6, lane = tid & 63;
  const int bid = blockIdx.x;
  const int bk = bid & 7;  // same-bk blocks land on same XCD (bid%8)
  // balanced pairing: co-resident bid and bid+256 have complementary work
  const int qt = (bid < 256) ? (bid >> 3) : 63 - ((bid - 256) >> 3);
  const int b = bk >> 2;
  const int hl = wid & 3, qs = wid >> 2;
  const int h = (bk & 3) * G_ + hl;
  const int qrow0 = qt * 32 + qs * 16;
  const int l15 = lane & 15, g4 = lane >> 4, kk = g4 * 8;
  const int swz = (l15 & 7) << 4;

  // ---- fused Q: load + RMSNorm + RoPE (row = qrow0 + l15) ----
  const int qrow = qrow0 + l15;
  const bf16* qsrc = QKV + (size_t)(b * L_ + qrow) * NQKV_ + h * D_;
  float t[4][8];
  float ss = 0.f;
#pragma unroll
  for (int c = 0; c < 4; ++c) {
    bf16x8 v = *reinterpret_cast<const bf16x8*>(qsrc + c * 32 + kk);
#pragma unroll
    for (int j = 0; j < 8; ++j) { t[c][j] = (float)v[j]; ss += t[c][j] * t[c][j]; }
  }

  // staging coordinates (pre-swizzled global sources, linear LDS dest)
  const int kr0 = tid >> 4, kc0 = tid & 15;
  const int kr1 = 32 + kr0;
  const int vr0 = tid >> 3, vc0 = tid & 7;
  const int vr1 = 64 + vr0;
  const bf16* kb = Kn + (size_t)bk * L_ * D_;
  const bf16* vb = Vt + (size_t)bk * D_ * (size_t)L_;
  const bf16* kp0 = kb + (size_t)kr0 * D_ + ((kc0 ^ (kr0 & 7)) * 8);
  const bf16* kp1 = kb + (size_t)kr1 * D_ + ((kc0 ^ (kr1 & 7)) * 8);
  const bf16* vp0 = vb + (size_t)vr0 * L_ + ((vc0 ^ (vr0 & 7)) * 8);
  const bf16* vp1 = vb + (size_t)vr1 * L_ + ((vc0 ^ (vr1 & 7)) * 8);

  const int ntiles = ((qt >> 3) + 1) * 4;  // multiple of 4 -> kt-unroll-2 safe
  // prologue stage tile 0 -> buf 0 (flies while we do Q norm math)
  gload16(kp0, smem + SM_K0 + tid * 16);
  gload16(kp1, smem + SM_K0 + 8192 + tid * 16);
  gload16(vp0, smem + SM_V0 + tid * 16);
  gload16(vp1, smem + SM_V0 + 8192 + tid * 16);

  // Q norm math (overlaps staging); fold scale*log2e into Q fragments
  constexpr float SCL = 0.12752650038632816f;  // 128^-0.5 * log2(e)
  ss += __shfl_xor(ss, 16);
  ss += __shfl_xor(ss, 32);
  const float rr = rsqrtf(ss * (1.0f / 128.0f) + 1e-6f);
  bf16x8 qf[4];
#pragma unroll
  for (int c = 0; c < 2; ++c)
#pragma unroll
    for (int j = 0; j < 8; ++j) {
      int i = c * 32 + kk + j;
      float n1 = t[c][j] * rr * qnw[i];
      float n2 = t[c + 2][j] * rr * qnw[i + 64];
      float cs = cosb[qrow * 64 + i], sn = sinb[qrow * 64 + i];
      qf[c][j] = (bf16)((n1 * cs - n2 * sn) * SCL);
      qf[c + 2][j] = (bf16)((n2 * cs + n1 * sn) * SCL);
    }

  // ---- loop-invariant LDS byte addresses (kept in VGPRs) ----
  int aK[4], aV[2], aPw[4];
#pragma unroll
  for (int c = 0; c < 4; ++c)
    aK[c] = l15 * 256 + ((((c << 2) + g4) ^ (l15 & 7)) << 4);
#pragma unroll
  for (int hh = 0; hh < 2; ++hh)
    aV[hh] = l15 * 128 + ((((hh << 2) + g4) ^ (l15 & 7)) << 4);
  const int pbase = SM_P + wid * 2048 + l15 * 128;
#pragma unroll
  for (int n = 0; n < 4; ++n)
    aPw[n] = pbase + (((n << 5) + (g4 << 3)) ^ swz);
  const int aPr0 = pbase + ((g4 << 4) ^ swz);
  const int aPr1 = pbase + ((64 + (g4 << 4)) ^ swz);

  f32x4 acc[8] = {};
  float mref = -1e30f, lpart = 0.f;

  __syncthreads();  // tile 0 staged (compiler drains vmcnt before barrier)

  // one kv-tile step; buffers are compile-time constants via manual unroll-2
  auto tile_step = [&](int KB, int VB, int KBn, int VBn, int ktNext, bool doPref) {
    if (doPref) {
      gload16(kp0 + (size_t)ktNext * 64 * D_, smem + KBn + tid * 16);
      gload16(kp1 + (size_t)ktNext * 64 * D_, smem + KBn + 8192 + tid * 16);
      gload16(vp0 + ktNext * 64, smem + VBn + tid * 16);
      gload16(vp1 + ktNext * 64, smem + VBn + 8192 + tid * 16);
    }
    // --- swapped QK^T: s[n][r] = Sscaled[qrow=l15][key=16n+4g4+r] ---
    f32x4 s[4];
    __builtin_amdgcn_s_setprio(1);
#pragma unroll
    for (int n = 0; n < 4; ++n) {
      f32x4 st = {};
#pragma unroll
      for (int c = 0; c < 4; ++c) {
        bf16x8 kf = *reinterpret_cast<const bf16x8*>(smem + KB + n * 4096 + aK[c]);
        st = __builtin_amdgcn_mfma_f32_16x16x32_bf16(kf, qf[c], st, 0, 0, 0);
      }
      s[n] = st;
    }
    __builtin_amdgcn_s_setprio(0);
    // --- defer-max online softmax (scalar per lane: one q-row) ---
    float pm = fmaxf(fmaxf(s[0][0], s[0][1]), fmaxf(s[0][2], s[0][3]));
#pragma unroll
    for (int n = 1; n < 4; ++n)
      pm = fmaxf(pm, fmaxf(fmaxf(s[n][0], s[n][1]), fmaxf(s[n][2], s[n][3])));
    if (!__all(pm <= mref + 8.f)) {  // rare: true max grew -> reduce, rescale
      pm = fmaxf(pm, __shfl_xor(pm, 16));
      pm = fmaxf(pm, __shfl_xor(pm, 32));
      float mnew = fmaxf(mref, pm);
      float resc = exp2f(mref - mnew);
      mref = mnew;
      lpart *= resc;
#pragma unroll
      for (int f = 0; f < 8; ++f) acc[f] *= resc;
    }
#pragma unroll
    for (int n = 0; n < 4; ++n)
#pragma unroll
      for (int r = 0; r < 4; ++r) {
        float p = exp2f(s[n][r] - mref);
        s[n][r] = p;
        lpart += p;
      }
    // --- P -> LDS: 4 x ds_write_b64 (precomputed addrs, wave-private) ---
#pragma unroll
    for (int n = 0; n < 4; ++n) {
      bf16x4 pw = {(bf16)s[n][0], (bf16)s[n][1], (bf16)s[n][2], (bf16)s[n][3]};
      *reinterpret_cast<bf16x4*>(smem + aPw[n]) = pw;
    }
    bf16x8 pf0 = *reinterpret_cast<const bf16x8*>(smem + aPr0);
    bf16x8 pf1 = *reinterpret_cast<const bf16x8*>(smem + aPr1);
    // --- PV: O^T = mfma(V^T, P^T) ---
    __builtin_amdgcn_s_setprio(1);
#pragma unroll
    for (int f = 0; f < 8; ++f) {
      bf16x8 vf0 = *reinterpret_cast<const bf16x8*>(smem + VB + f * 2048 + aV[0]);
      acc[f] = __builtin_amdgcn_mfma_f32_16x16x32_bf16(vf0, pf0, acc[f], 0, 0, 0);
      bf16x8 vf1 = *reinterpret_cast<const bf16x8*>(smem + VB + f * 2048 + aV[1]);
      acc[f] = __builtin_amdgcn_mfma_f32_16x16x32_bf16(vf1, pf1, acc[f], 0, 0, 0);
    }
    __builtin_amdgcn_s_setprio(0);
    __syncthreads();  // drains this iter's prefetch (late) + releases buffers
  };

  for (int kt = 0; kt < ntiles; kt += 2) {
    tile_step(SM_K0, SM_V0, SM_K1, SM_V1, kt + 1, true);
    tile_step(SM_K1, SM_V1, SM_K0, SM_V0, kt + 2, kt + 2 < ntiles);
  }

  // --- epilogue: reduce row-sum over the 4 lane-groups, packed stores ---
  lpart += __shfl_xor(lpart, 16);
  lpart += __shfl_xor(lpart, 32);
  const float rinv = 1.f / lpart;
  bf16* aop = AO + ((size_t)(b * L_ + qrow0 + l15) * H_ + h) * D_ + (g4 << 2);
#pragma unroll
  for (int f = 0; f < 8; ++f) {
    bf16x4 o = {(bf16)(acc[f][0] * rinv), (bf16)(acc[f][1] * rinv),
                (bf16)(acc[f][2] * rinv), (bf16)(acc[f][3] * rinv)};
    *reinterpret_cast<bf16x4*>(aop + f * 16) = o;
  }
}

// ---------------- launch ----------------
extern "C" void kernel_launch(void* const* d_in, const int* in_sizes, int n_in,
                              void* d_out, int out_size, void* d_ws, size_t ws_size,
                              hipStream_t stream) {
  const float* x = (const float*)d_in[0];
  const float* Wq = (const float*)d_in[1];
  const float* Wk = (const float*)d_in[2];
  const float* Wv = (const float*)d_in[3];
  const float* Wo = (const float*)d_in[4];
  const float* qnw = (const float*)d_in[5];
  const float* knw = (const float*)d_in[6];
  const float* rc = (const float*)d_in[7];
  const float* rs = (const float*)d_in[8];
  float* out = (float*)d_out;

  char* ws = (char*)d_ws;
  bf16* xb = (bf16*)ws;    ws += (size_t)TOK_ * C_ * 2;
  bf16* wqb = (bf16*)ws;   ws += (size_t)(H_ * D_) * C_ * 2;   // wq/wk/wv contiguous!
  bf16* wkb = (bf16*)ws;   ws += (size_t)(HKV_ * D_) * C_ * 2;
  bf16* wvb = (bf16*)ws;   ws += (size_t)(HKV_ * D_) * C_ * 2;
  bf16* wob = (bf16*)ws;   ws += (size_t)C_ * (H_ * D_) * 2;
  bf16* qkv = (bf16*)ws;   ws += (size_t)TOK_ * NQKV_ * 2;
  bf16* Kb = (bf16*)ws;    ws += (size_t)TOK_ * HKV_ * D_ * 2;
  bf16* Vtb = (bf16*)ws;   ws += (size_t)TOK_ * HKV_ * D_ * 2;
  bf16* AOb = xb;  // alias: xb dead after projection GEMM

  // single fused conversion (dsts xb..wob are contiguous)
  cvt_all<<<2048, 256, 0, stream>>>(x, Wq, Wk, Wv, Wo, xb);

  // fused QKV projection: N = 3072 (wq,wk,wv rows contiguous)
  gemm_bt<false><<<dim3(TOK_ / 128, NQKV_ / 128), 256, 0, stream>>>(
      xb, wqb, qkv, TOK_, NQKV_, C_);

  k_norm_rope<<<(TOK_ * HKV_) / 4, 256, 0, stream>>>(qkv, knw, rc, rs, Kb);
  v_transpose<<<dim3(L_ / 64, B_ * HKV_), 256, 0, stream>>>(qkv, Vtb);

  attn_fused<<<512, 512, 0, stream>>>(qkv, Kb, Vtb, qnw, rc, rs, AOb);

  gemm_bt<true><<<dim3(TOK_ / 128, C_ / 128), 256, 0, stream>>>(
      AOb, wob, out, TOK_, C_, H_ * D_);
}